// Round 6
// baseline (206.666 us; speedup 1.0000x reference)
//
#include <hip/hip_runtime.h>
#include <hip/hip_cooperative_groups.h>
#include <stdint.h>

namespace cg = cooperative_groups;

// Problem constants (match reference)
#define B_ 4096
#define C_ 200
#define P_ 32
#define F_ 512
#define N_ (C_*P_)        // 6400 prototypes total
#define ALPHA_ 5.0
#define EPS_ 1e-8

typedef unsigned char u8;
typedef __attribute__((ext_vector_type(4))) float floatx4;  // MFMA C/D frag

union frag16 { int4 v; long l[2]; };   // 16 fp8 = two MFMA k-slices (virtual-K)

#define BM 256
#define BN 256

typedef const __attribute__((address_space(1))) unsigned int gu32_t;
typedef __attribute__((address_space(3))) unsigned int lu32_t;

__device__ __forceinline__ void gld16(const u8* g, u8* l) {
    __builtin_amdgcn_global_load_lds((gu32_t*)g, (lu32_t*)l, 16, 0, 0);
}

// ---------------- ONE fused cooperative kernel: prep | score | select | finalize --------
// Grid = 256 blocks x 1024 threads, 96KB LDS -> exactly 1 block/CU, all co-resident.
// Phases separated by cg::grid.sync(). Each phase is the previously-proven standalone
// implementation re-indexed for a persistent 256-block grid. Rationale: removes 3
// kernel-launch boundaries (tests the fixed-overhead hypothesis) and makes the fused
// dispatch large enough to clear the ~43us fill-dispatch cutoff -> direct counters.
__global__ __launch_bounds__(1024)
void fused_kernel(const float* __restrict__ outputs, const float* __restrict__ clusters,
                  const int* __restrict__ tgt,
                  u8* __restrict__ At, u8* __restrict__ Bt,
                  float* __restrict__ sumsq, float* __restrict__ min_d,
                  float* __restrict__ stw, float* __restrict__ sww,
                  float* __restrict__ out) {
    __shared__ __align__(16) union {
        u8    buf[3][32768];     // score: triple-buffered A|B tiles
        float red[2][8][16];     // prep: per-half kc-partial sumsq
        float sel[2][16][64];    // select: [bw|vt][slice][sample]
        float fin[2][16];        // finalize
    } sh;

    cg::grid_group grid = cg::this_grid();
    const int tid = threadIdx.x;
    const int blk = blockIdx.x;

    // ---------- phase 1: prep (fp32 -> fp8 e4m3 packed + row sumsq) ----------
    // 656 16-row groups = 328 units of 2; unit u -> halves (tid<512 | tid>=512).
    {
        const int half = tid >> 9, ht = tid & 511;
        const int kc = ht >> 6, q = (ht >> 4) & 3, r = ht & 15;
        for (int u = blk; u < 328; u += 256) {
            const int g = u * 2 + half;
            const float* src; u8* dst; int tm;
            if (g < 256) { tm = g;       src = outputs;  dst = At; }
            else         { tm = g - 256; src = clusters; dst = Bt; }
            const int row = tm * 16 + r;
            const float4* s = (const float4*)(src + (size_t)row * F_ + kc * 64 + q * 16);
            float4 v0 = s[0], v1 = s[1], v2 = s[2], v3 = s[3];
            int4 w;
            w.x = __builtin_amdgcn_cvt_pk_fp8_f32(v0.x, v0.y, 0, false);
            w.x = __builtin_amdgcn_cvt_pk_fp8_f32(v0.z, v0.w, w.x, true);
            w.y = __builtin_amdgcn_cvt_pk_fp8_f32(v1.x, v1.y, 0, false);
            w.y = __builtin_amdgcn_cvt_pk_fp8_f32(v1.z, v1.w, w.y, true);
            w.z = __builtin_amdgcn_cvt_pk_fp8_f32(v2.x, v2.y, 0, false);
            w.z = __builtin_amdgcn_cvt_pk_fp8_f32(v2.z, v2.w, w.z, true);
            w.w = __builtin_amdgcn_cvt_pk_fp8_f32(v3.x, v3.y, 0, false);
            w.w = __builtin_amdgcn_cvt_pk_fp8_f32(v3.z, v3.w, w.w, true);
            *(int4*)(dst + (size_t)(tm * 512 + ht) * 16) = w;

            float ss = v0.x*v0.x + v0.y*v0.y + v0.z*v0.z + v0.w*v0.w
                     + v1.x*v1.x + v1.y*v1.y + v1.z*v1.z + v1.w*v1.w
                     + v2.x*v2.x + v2.y*v2.y + v2.z*v2.z + v2.w*v2.w
                     + v3.x*v3.x + v3.y*v3.y + v3.z*v3.z + v3.w*v3.w;
            ss += __shfl_xor(ss, 16);        // fold q^1
            ss += __shfl_xor(ss, 32);        // fold q^2
            if ((ht & 63) < 16) sh.red[half][kc][r] = ss;
            __syncthreads();
            if (tid < 32) {
                const int hh = tid >> 4, rr = tid & 15;
                const int gg = u * 2 + hh;
                const int rb  = (gg < 256) ? 0 : B_;
                const int tmm = (gg < 256) ? gg : gg - 256;
                float t = 0.f;
#pragma unroll
                for (int k = 0; k < 8; ++k) t += sh.red[hh][k][rr];
                sumsq[rb + tmm * 16 + rr] = t;
            }
            __syncthreads();
        }
    }
    grid.sync();

    // ---------- phase 2: score (256x256 tile fp8 MFMA GEMM, triple-buffer, vmcnt(2)) ----
    {
        const float* p2 = sumsq + B_;
        const int lane = tid & 63;
        const int w    = tid >> 6;          // wave 0..15 (4x4 grid, 64x64 per wave)
        const int wm   = w >> 2, wn = w & 3;
        const int mrow = lane & 15;
        const int quad = lane >> 4;
        const int l16  = lane * 16;

        for (int t = blk; t < 400; t += 256) {
            // same bijective XCD mapping as before (persistent block's XCD = blk&7)
            const int xcd = t & 7, rr = t >> 3;
            const int bx = rr % 25, by = xcd * 2 + rr / 25;

            const u8* ag = At + ((size_t)(by * 16) << 13);
            const u8* bg = Bt + ((size_t)(bx * 16) << 13);

            // tile-top barrier: all waves' previous-tile LDS reads are complete at
            // arrival (MFMA operand lgkmcnt waits precede epilogue), so buffer reuse
            // below is race-free.
            __syncthreads();

            floatx4 zf = {0.f, 0.f, 0.f, 0.f};
            floatx4 acc[4][4];
#pragma unroll
            for (int i = 0; i < 4; ++i)
#pragma unroll
                for (int j = 0; j < 4; ++j) acc[i][j] = zf;

#define ISSUE(s, b)                                                            \
    do {                                                                       \
        gld16(ag + ((w * 8 + (s)) << 10) + l16, sh.buf[b] + w * 1024);         \
        gld16(bg + ((w * 8 + (s)) << 10) + l16, sh.buf[b] + 16384 + w * 1024); \
    } while (0)

            ISSUE(0, 0);
            ISSUE(1, 1);

#pragma unroll
            for (int kc = 0; kc < 8; ++kc) {
                if (kc < 7) asm volatile("s_waitcnt vmcnt(2)" ::: "memory");
                else        asm volatile("s_waitcnt vmcnt(0)" ::: "memory");
                __builtin_amdgcn_s_barrier();
                if (kc < 6) ISSUE(kc + 2, (kc + 2) % 3);

                const u8* L = sh.buf[kc % 3];
                frag16 a[4], b[4];
#pragma unroll
                for (int tt = 0; tt < 4; ++tt) {
                    a[tt].v = *(const int4*)(L + (wm * 4 + tt) * 1024 + l16);
                    b[tt].v = *(const int4*)(L + 16384 + (wn * 4 + tt) * 1024 + l16);
                }
#pragma unroll
                for (int s = 0; s < 2; ++s)
#pragma unroll
                    for (int mt = 0; mt < 4; ++mt)
#pragma unroll
                        for (int nt = 0; nt < 4; ++nt)
                            acc[mt][nt] = __builtin_amdgcn_mfma_f32_16x16x32_fp8_fp8(
                                a[mt].l[s], b[nt].l[s], acc[mt][nt], 0, 0, 0);
            }
#undef ISSUE

            // Epilogue: score = p2[n] - 2*xp; per-class min over 32 protos.
            // C/D: col = lane&15, row = quad*4 + reg. Transposed store min_d[cls*B+row],
            // one float4 per quad-lane (4 quads = contiguous 64B).
            float pg[4];
#pragma unroll
            for (int nt = 0; nt < 4; ++nt) pg[nt] = p2[bx * BN + wn * 64 + nt * 16 + mrow];

#pragma unroll
            for (int ch = 0; ch < 2; ++ch) {
                const int cls = bx * 8 + wn * 2 + ch;
#pragma unroll
                for (int mt = 0; mt < 4; ++mt) {
                    float4 vv;
#pragma unroll
                    for (int reg = 0; reg < 4; ++reg) {
                        float v = fminf(pg[ch * 2]     - 2.0f * acc[mt][ch * 2][reg],
                                        pg[ch * 2 + 1] - 2.0f * acc[mt][ch * 2 + 1][reg]);
#pragma unroll
                        for (int m = 8; m >= 1; m >>= 1) v = fminf(v, __shfl_xor(v, m));
                        ((float*)&vv)[reg] = v;
                    }
                    if (mrow == 0) {
                        int grow = by * BM + wm * 64 + mt * 16 + quad * 4;
                        *(float4*)&min_d[(size_t)cls * B_ + grow] = vv;
                    }
                }
            }
        }
    }
    grid.sync();

    // ---------- phase 3: select (blocks 0..63; 64 samples x 16 class-slices) ----------
    if (blk < 64) {
        const int sb = tid & 63;             // sample within block (= lane -> coalesced)
        const int sl = tid >> 6;             // class-slice 0..15 (= wave)
        const int b  = blk * 64 + sb;
        const int tc = tgt[b];

        float bw = 3.4e38f, vt = 3.4e38f;
        for (int c = sl; c < C_; c += 16) {
            float v = min_d[(size_t)c * B_ + b];
            if (c == tc) vt = v;
            else         bw = fminf(bw, v);
        }
        sh.sel[0][sl][sb] = bw;
        sh.sel[1][sl][sb] = vt;
        __syncthreads();
        if (tid < 64) {
            float fb = 3.4e38f, fv = 3.4e38f;
#pragma unroll
            for (int k = 0; k < 16; ++k) {
                fb = fminf(fb, sh.sel[0][k][tid]);
                fv = fminf(fv, sh.sel[1][k][tid]);
            }
            const int bb = blk * 64 + tid;
            float xx = sumsq[bb];            // x2
            stw[bb] = xx + fv;               // = ||x - p_target*||^2 (fp8-dot approx)
            sww[bb] = xx + fb;               // = ||x - p_wrong*||^2
        }
    }
    grid.sync();

    // ---------- phase 4: finalize (block 0) ----------
    if (blk == 0) {
        float s1 = 0.f, s2 = 0.f;
#pragma unroll
        for (int i = 0; i < 4; ++i) {
            s1 += stw[tid + i * 1024];
            s2 += sww[tid + i * 1024];
        }
#pragma unroll
        for (int m = 32; m >= 1; m >>= 1) { s1 += __shfl_xor(s1, m); s2 += __shfl_xor(s2, m); }
        if ((tid & 63) == 0) { sh.fin[0][tid >> 6] = s1; sh.fin[1][tid >> 6] = s2; }
        __syncthreads();
        if (tid == 0) {
            double t1 = 0.0, t2 = 0.0;
#pragma unroll
            for (int i = 0; i < 16; ++i) { t1 += (double)sh.fin[0][i]; t2 += (double)sh.fin[1][i]; }
            double denom = (double)B_ * (double)F_;
            double tl  = t1 / denom;
            double ntl = t2 / denom;
            out[0] = (float)((1.0 - ALPHA_) * tl + ALPHA_ / (ntl + EPS_));
        }
    }
}

// ---------- launch ----------
extern "C" void kernel_launch(void* const* d_in, const int* in_sizes, int n_in,
                              void* d_out, int out_size, void* d_ws, size_t ws_size,
                              hipStream_t stream) {
    const float* outputs  = (const float*)d_in[0];
    const float* clusters = (const float*)d_in[1];
    const int*   tgt      = (const int*)d_in[2];
    float* out = (float*)d_out;

    char* ws = (char*)d_ws;
    // workspace layout (16B-aligned)
    u8*     At      = (u8*)(ws);                     // packed A: 2,097,152
    u8*     Bt      = (u8*)(ws + 2097152);           // packed B: 3,276,800
    float*  sumsq   = (float*)(ws + 5373952);        // 10496*4 (x2 | p2)
    float*  min_d   = (float*)(ws + 5415936);        // [C][B] 200*4096*4
    // per-sample partials: live AFTER score (At region is dead by then)
    float*  stw     = (float*)(ws);                  // 4096*4
    float*  sww     = (float*)(ws + 16384);          // 4096*4

    void* args[] = { (void*)&outputs, (void*)&clusters, (void*)&tgt,
                     (void*)&At, (void*)&Bt, (void*)&sumsq, (void*)&min_d,
                     (void*)&stw, (void*)&sww, (void*)&out };
    hipLaunchCooperativeKernel((void*)fused_kernel, dim3(256), dim3(1024), args, 0, stream);
}

// Round 7
// 108.396 us; speedup vs baseline: 1.9066x; 1.9066x over previous
//
#include <hip/hip_runtime.h>
#include <stdint.h>

// Problem constants (match reference)
#define B_ 4096
#define C_ 200
#define P_ 32
#define F_ 512
#define N_ (C_*P_)        // 6400 prototypes total
#define ALPHA_ 5.0
#define EPS_ 1e-8

typedef unsigned char u8;
typedef __attribute__((ext_vector_type(4))) float floatx4;  // MFMA C/D frag

union frag16 { int4 v; long l[2]; };   // 16 fp8 = two MFMA k-slices (virtual-K)

// ---------- prep: fp32 -> fp8 e4m3 packed + row sum-of-squares (x2 | p2) ----------
// Proven R5 version: block = 512 threads = 8 waves = kc 0..7 of ONE 16-row group.
__global__ __launch_bounds__(512)
void prep_kernel(const float* __restrict__ outputs, const float* __restrict__ clusters,
                 u8* __restrict__ At, u8* __restrict__ Bt, float* __restrict__ sumsq) {
    const int tid = threadIdx.x;
    const int blk = blockIdx.x;
    const float* src; u8* dst; int tm, rbase;
    if (blk < B_ / 16) { tm = blk;            src = outputs;  dst = At; rbase = 0;  }
    else               { tm = blk - B_ / 16;  src = clusters; dst = Bt; rbase = B_; }
    const int o  = tm * 512 + tid;           // packed 16B-unit index
    const int kc = tid >> 6, q = (tid >> 4) & 3, r = tid & 15;
    const int row = tm * 16 + r;

    const float4* s = (const float4*)(src + (size_t)row * F_ + kc * 64 + q * 16);
    float4 v0 = s[0], v1 = s[1], v2 = s[2], v3 = s[3];
    int4 w;
    w.x = __builtin_amdgcn_cvt_pk_fp8_f32(v0.x, v0.y, 0, false);
    w.x = __builtin_amdgcn_cvt_pk_fp8_f32(v0.z, v0.w, w.x, true);
    w.y = __builtin_amdgcn_cvt_pk_fp8_f32(v1.x, v1.y, 0, false);
    w.y = __builtin_amdgcn_cvt_pk_fp8_f32(v1.z, v1.w, w.y, true);
    w.z = __builtin_amdgcn_cvt_pk_fp8_f32(v2.x, v2.y, 0, false);
    w.z = __builtin_amdgcn_cvt_pk_fp8_f32(v2.z, v2.w, w.z, true);
    w.w = __builtin_amdgcn_cvt_pk_fp8_f32(v3.x, v3.y, 0, false);
    w.w = __builtin_amdgcn_cvt_pk_fp8_f32(v3.z, v3.w, w.w, true);
    *(int4*)(dst + (size_t)o * 16) = w;

    float ss = v0.x*v0.x + v0.y*v0.y + v0.z*v0.z + v0.w*v0.w
             + v1.x*v1.x + v1.y*v1.y + v1.z*v1.z + v1.w*v1.w
             + v2.x*v2.x + v2.y*v2.y + v2.z*v2.z + v2.w*v2.w
             + v3.x*v3.x + v3.y*v3.y + v3.z*v3.z + v3.w*v3.w;
    ss += __shfl_xor(ss, 16);                // fold q^1
    ss += __shfl_xor(ss, 32);                // fold q^2 -> per-row partial (this kc)
    __shared__ float red[8][16];
    if ((tid & 63) < 16) red[kc][r] = ss;
    __syncthreads();
    if (tid < 16) {
        float t = 0.f;
#pragma unroll
        for (int k = 0; k < 8; ++k) t += red[k][tid];
        sumsq[rbase + tm * 16 + tid] = t;
    }
}

// ---------- score kernel: BARRIER-FREE K-loop ----------
// Round-6 direct counters (MfmaUtil 8%, VALU 7%, HBM 4%, conflicts 0) showed the GEMM is
// latency/sync-bound: every K-stage coupled 16 waves through waitcnt+barrier on staged LDS.
// Fix: exploit that the packed layout makes a lane's 16B unit the exact MFMA fragment, so
// A is consumed DIRECTLY from global (L2-resident: by=bid&7 pins each 256KB A-panel to one
// XCD). B-tile (64 protos x 512K = 32KB, contiguous in Bt) is staged to LDS once -> ONE
// barrier per block, then waves run completely free: per kc, 4 global A-frag loads + 4 LDS
// B-frag reads + 32 MFMA. No lockstep, load latency hides under MFMAs across 16 waves/CU.
#define BMs 512
#define BNs 64

typedef const __attribute__((address_space(1))) unsigned int gu32_t;
typedef __attribute__((address_space(3))) unsigned int lu32_t;

__device__ __forceinline__ void gld16(const u8* g, u8* l) {
    __builtin_amdgcn_global_load_lds((gu32_t*)g, (lu32_t*)l, 16, 0, 0);
}

__global__ __launch_bounds__(512, 4)
void score_kernel(const u8* __restrict__ At, const u8* __restrict__ Bt,
                  const float* __restrict__ p2, float* __restrict__ min_d) {
    __shared__ __align__(16) u8 ldsB[32768];   // B-tile: 4 col-subtiles x 8 kc x 1KB

    const int tid  = threadIdx.x;
    const int lane = tid & 63;
    const int w    = tid >> 6;            // wave 0..7, owns rows [w*64, +64) of the m-panel
    const int mrow = lane & 15;
    const int quad = lane >> 4;
    const int l16  = lane * 16;

    const int bid = blockIdx.x;           // 800 blocks
    const int by  = bid & 7;              // m-panel 0..7 (= XCD under round-robin dispatch)
    const int bx  = bid >> 3;             // n-tile 0..99

    // stage the whole 32KB B-tile (contiguous in Bt) once; lane-linear dest
#pragma unroll
    for (int i = 0; i < 4; ++i)
        gld16(Bt + (size_t)bx * 32768 + i * 8192 + tid * 16, ldsB + i * 8192 + tid * 16);
    asm volatile("s_waitcnt vmcnt(0)" ::: "memory");
    __syncthreads();

    floatx4 zf = {0.f, 0.f, 0.f, 0.f};
    floatx4 acc[4][4];
#pragma unroll
    for (int i = 0; i < 4; ++i)
#pragma unroll
        for (int j = 0; j < 4; ++j) acc[i][j] = zf;

    // A row-subtile base: rows (by*512 + w*64 + t*16 .. +16) -> subtile index by*32+w*4+t
    const u8* ap = At + (((size_t)(by * 32 + w * 4)) << 13);   // 4 subtiles x 8KB

#pragma unroll
    for (int kc = 0; kc < 8; ++kc) {
        frag16 a[4], b[4];
#pragma unroll
        for (int t = 0; t < 4; ++t)
            a[t].v = *(const int4*)(ap + ((t * 8 + kc) << 10) + l16);
#pragma unroll
        for (int t = 0; t < 4; ++t)
            b[t].v = *(const int4*)(ldsB + ((t * 8 + kc) << 10) + l16);
#pragma unroll
        for (int s = 0; s < 2; ++s)
#pragma unroll
            for (int mt = 0; mt < 4; ++mt)
#pragma unroll
                for (int nt = 0; nt < 4; ++nt)
                    acc[mt][nt] = __builtin_amdgcn_mfma_f32_16x16x32_fp8_fp8(
                        a[mt].l[s], b[nt].l[s], acc[mt][nt], 0, 0, 0);
    }

    // Epilogue: score = p2[n] - 2*xp; per-class min over 32 protos (2 classes per tile).
    // C/D: col = lane&15 (proto), row = quad*4 + reg (sample). Transposed store
    // min_d[cls*B + row]: one float4 per quad-lane, 4 quads = contiguous 64B.
    float pg[4];
#pragma unroll
    for (int nt = 0; nt < 4; ++nt) pg[nt] = p2[bx * BNs + nt * 16 + mrow];

#pragma unroll
    for (int ch = 0; ch < 2; ++ch) {
        const int cls = bx * 2 + ch;
#pragma unroll
        for (int mt = 0; mt < 4; ++mt) {
            float4 vv;
#pragma unroll
            for (int reg = 0; reg < 4; ++reg) {
                float v = fminf(pg[ch * 2]     - 2.0f * acc[mt][ch * 2][reg],
                                pg[ch * 2 + 1] - 2.0f * acc[mt][ch * 2 + 1][reg]);
#pragma unroll
                for (int m = 8; m >= 1; m >>= 1) v = fminf(v, __shfl_xor(v, m));
                ((float*)&vv)[reg] = v;
            }
            if (mrow == 0) {
                int grow = by * BMs + w * 64 + mt * 16 + quad * 4;
                *(float4*)&min_d[(size_t)cls * B_ + grow] = vv;
            }
        }
    }
}

// ---------- per-sample select: [C][B] layout, class-parallel (proven R5) ----------
__global__ __launch_bounds__(256)
void select_kernel(const float* __restrict__ min_d, const float* __restrict__ x2,
                   const int* __restrict__ tgt,
                   float* __restrict__ stw, float* __restrict__ sww) {
    const int sb = threadIdx.x & 15;        // sample within block
    const int sl = threadIdx.x >> 4;        // class-slice 0..15
    const int b  = blockIdx.x * 16 + sb;
    const int tc = tgt[b];

    float bw = 3.4e38f, vt = 3.4e38f;
    for (int c = sl; c < C_; c += 16) {
        float v = min_d[(size_t)c * B_ + b];
        if (c == tc) vt = v;
        else         bw = fminf(bw, v);
    }
    bw = fminf(bw, __shfl_xor(bw, 16));
    bw = fminf(bw, __shfl_xor(bw, 32));
    vt = fminf(vt, __shfl_xor(vt, 16));
    vt = fminf(vt, __shfl_xor(vt, 32));

    __shared__ float rbw[4][16], rvt[4][16];
    const int w = threadIdx.x >> 6;
    if ((threadIdx.x & 63) < 16) { rbw[w][sb] = bw; rvt[w][sb] = vt; }
    __syncthreads();
    if (threadIdx.x < 16) {
        float fb = fminf(fminf(rbw[0][sb], rbw[1][sb]), fminf(rbw[2][sb], rbw[3][sb]));
        float fv = fminf(fminf(rvt[0][sb], rvt[1][sb]), fminf(rvt[2][sb], rvt[3][sb]));
        float xx = x2[b];
        stw[b] = xx + fv;        // = ||x - p_target*||^2 (fp8-dot approx)
        sww[b] = xx + fb;        // = ||x - p_wrong*||^2
    }
}

// Single-block reduction of 2x4096 floats + final loss
__global__ __launch_bounds__(1024)
void finalize_kernel(const float* __restrict__ stw, const float* __restrict__ sww,
                     float* __restrict__ out) {
    __shared__ float r1[16], r2[16];
    int tid = threadIdx.x;
    float s1 = 0.f, s2 = 0.f;
#pragma unroll
    for (int i = 0; i < 4; ++i) {
        s1 += stw[tid + i * 1024];
        s2 += sww[tid + i * 1024];
    }
#pragma unroll
    for (int m = 32; m >= 1; m >>= 1) { s1 += __shfl_xor(s1, m); s2 += __shfl_xor(s2, m); }
    if ((tid & 63) == 0) { r1[tid >> 6] = s1; r2[tid >> 6] = s2; }
    __syncthreads();
    if (tid == 0) {
        double t1 = 0.0, t2 = 0.0;
#pragma unroll
        for (int i = 0; i < 16; ++i) { t1 += (double)r1[i]; t2 += (double)r2[i]; }
        double denom = (double)B_ * (double)F_;
        double tl  = t1 / denom;
        double ntl = t2 / denom;
        out[0] = (float)((1.0 - ALPHA_) * tl + ALPHA_ / (ntl + EPS_));
    }
}

// ---------- launch ----------
extern "C" void kernel_launch(void* const* d_in, const int* in_sizes, int n_in,
                              void* d_out, int out_size, void* d_ws, size_t ws_size,
                              hipStream_t stream) {
    const float* outputs  = (const float*)d_in[0];
    const float* clusters = (const float*)d_in[1];
    const int*   tgt      = (const int*)d_in[2];
    float* out = (float*)d_out;

    char* ws = (char*)d_ws;
    // workspace layout (16B-aligned)
    u8*     At      = (u8*)(ws);                     // packed A: 2,097,152
    u8*     Bt      = (u8*)(ws + 2097152);           // packed B: 3,276,800
    float*  sumsq   = (float*)(ws + 5373952);        // 10496*4 (x2 | p2)
    float*  min_d   = (float*)(ws + 5415936);        // [C][B] 200*4096*4
    float*  x2      = sumsq;
    float*  p2      = sumsq + B_;
    // per-sample partials: reuse the At region (dead after score_kernel)
    float*  stw     = (float*)(ws);                  // 4096*4
    float*  sww     = (float*)(ws + 16384);          // 4096*4

    prep_kernel<<<B_ / 16 + N_ / 16, 512, 0, stream>>>(outputs, clusters, At, Bt, sumsq); // 656
    score_kernel<<<(B_ / BMs) * (N_ / BNs), 512, 0, stream>>>(At, Bt, p2, min_d);         // 800
    select_kernel<<<B_ / 16, 256, 0, stream>>>(min_d, x2, tgt, stw, sww);                 // 256
    finalize_kernel<<<1, 1024, 0, stream>>>(stw, sww, out);
}